// Round 2
// baseline (14889.714 us; speedup 1.0000x reference)
//
#include <hip/hip_runtime.h>

// LSTM T=512 B=64 IN=512 H=512 L=2, fp32 in/out.
// Round 2: single persistent kernel (64 blocks, co-resident on 256 CUs) loops
// all 512 timesteps; cross-block sync via agent-scope atomic flags in ws.
// unit0 = layer0 (blocks 0..31), unit1 = layer1 (blocks 32..63), software
// pipelined one step apart. Inner GEMM identical to verified round-1 kernel:
// ifgo = [inp | h_prev](64x1024) @ Wcat^T + bh via bf16 16x16x32 MFMA.
// c lives in 4 VGPRs per thread for the entire sequence.

typedef unsigned short u16;
typedef unsigned int u32;
typedef __attribute__((ext_vector_type(8))) short bf16x8;
typedef __attribute__((ext_vector_type(4))) float floatx4;

#define T_ 512
#define B_ 64
#define H_ 512
#define BH (B_ * H_)

__device__ __forceinline__ u16 f2bf(float f) {
  u32 u = __float_as_uint(f);
  u32 r = (u + 0x7fffu + ((u >> 16) & 1u)) >> 16;  // RNE
  return (u16)r;
}

__device__ __forceinline__ float sigm(float x) { return 1.f / (1.f + __expf(-x)); }

__device__ __forceinline__ float tanh_(float x) {
  float ax = fabsf(x);
  float e = __expf(-2.f * ax);
  float t = (1.f - e) / (1.f + e);
  return copysignf(t, x);
}

// Wcat[l][row 0..2047][k 0..1023] bf16: k<512 from Wx, k>=512 from Wh.
__global__ void conv_w_kernel(const float* __restrict__ Wx, const float* __restrict__ Wh,
                              u16* __restrict__ Wcat) {
  int i = blockIdx.x * 256 + threadIdx.x;
  int base = i * 4;
  int k = base & 1023;
  int row = base >> 10;
  const float* src = (k < 512) ? (Wx + row * 512 + k) : (Wh + row * 512 + (k - 512));
  float4 v = *(const float4*)src;
  uint2 p;
  p.x = (u32)f2bf(v.x) | ((u32)f2bf(v.y) << 16);
  p.y = (u32)f2bf(v.z) | ((u32)f2bf(v.w) << 16);
  *(uint2*)(Wcat + base) = p;
}

__global__ void conv_x_kernel(const float4* __restrict__ x, u16* __restrict__ xb) {
  int i = blockIdx.x * 256 + threadIdx.x;
  float4 v = x[i];
  uint2 p;
  p.x = (u32)f2bf(v.x) | ((u32)f2bf(v.y) << 16);
  p.y = (u32)f2bf(v.z) | ((u32)f2bf(v.w) << 16);
  *(uint2*)(xb + i * 4) = p;
}

__global__ void init_flags(u32* flags) {
  if (threadIdx.x < 64) flags[threadIdx.x] = 0;
}

__device__ __forceinline__ void wait_ge(const u32* f, u32 target) {
  while (__hip_atomic_load(f, __ATOMIC_ACQUIRE, __HIP_MEMORY_SCOPE_AGENT) < target) {
    __builtin_amdgcn_s_sleep(1);
  }
}

// 64 blocks x 256 threads, persistent over all timesteps.
// Block = (unit = blockIdx>>5, blk = 16-col slice). Wave w = gate w.
// h0s/h1s: depth-4 slot buffers [4][64][512] bf16. flags[2][32]: step counts.
__global__ __launch_bounds__(256) void lstm_persist(
    const u16* __restrict__ Wcat, const float* __restrict__ bh,
    const u16* __restrict__ xb, u16* __restrict__ h0s, u16* __restrict__ h1s,
    u32* flags, float* __restrict__ out) {
  const int unit = blockIdx.x >> 5;
  const int blk = blockIdx.x & 31;
  const int tid = threadIdx.x;
  const int wave = tid >> 6;
  const int lane = tid & 63;
  const int nl = lane & 15;
  const int quad = lane >> 4;

  const u16* wrow = Wcat + ((size_t)unit * 2048 + wave * 512 + blk * 16 + nl) * 1024 + quad * 8;
  const float bias = bh[unit * 2048 + wave * 512 + blk * 16 + nl];

  __shared__ float lds[4][64][17];
  float creg[4] = {0.f, 0.f, 0.f, 0.f};  // c for rows rr*16+(tid>>4), col blk*16+(tid&15)

  u32* myflag = flags + unit * 32 + blk;
  const u32* spin0 = flags + (tid & 31);        // unit0 slice flags
  const u32* spin1 = flags + 32 + (tid & 31);   // unit1 slice flags

  const size_t out_h_base = (size_t)T_ * BH;
  const size_t out_c_base = out_h_base + 2 * (size_t)BH;

  for (int t = 0; t < T_; ++t) {
    floatx4 acc[4] = {floatx4{0.f, 0.f, 0.f, 0.f}, floatx4{0.f, 0.f, 0.f, 0.f},
                      floatx4{0.f, 0.f, 0.f, 0.f}, floatx4{0.f, 0.f, 0.f, 0.f}};

    if (unit == 0) {
      // ---- x-half: no dependency, compute while peers finish h0_{t-1} ----
      {
        const u16* abase = xb + (size_t)t * BH + quad * 8;
#pragma unroll 4
        for (int kk = 0; kk < 512; kk += 32) {
          bf16x8 bfrag = *(const bf16x8*)(wrow + kk);
#pragma unroll
          for (int r = 0; r < 4; ++r) {
            bf16x8 afrag = *(const bf16x8*)(abase + (r * 16 + nl) * H_ + kk);
            acc[r] = __builtin_amdgcn_mfma_f32_16x16x32_bf16(afrag, bfrag, acc[r], 0, 0, 0);
          }
        }
      }
      if (t > 0) wait_ge(spin0, (u32)t);             // h0_{t-1} complete
      if (t >= 4) wait_ge(spin1, (u32)(t - 3));      // back-pressure: slot t&3 free
      __syncthreads();
      if (t > 0) {
        const u16* abase = h0s + (size_t)((t - 1) & 3) * BH + quad * 8;
#pragma unroll 4
        for (int kk = 0; kk < 512; kk += 32) {
          bf16x8 bfrag = *(const bf16x8*)(wrow + 512 + kk);
#pragma unroll
          for (int r = 0; r < 4; ++r) {
            bf16x8 afrag = *(const bf16x8*)(abase + (r * 16 + nl) * H_ + kk);
            acc[r] = __builtin_amdgcn_mfma_f32_16x16x32_bf16(afrag, bfrag, acc[r], 0, 0, 0);
          }
        }
      }
    } else {
      // ---- h1_{t-1} half first (available one pipeline stage earlier) ----
      if (t > 0) {
        wait_ge(spin1, (u32)t);
        __syncthreads();
        const u16* abase = h1s + (size_t)((t - 1) & 3) * BH + quad * 8;
#pragma unroll 4
        for (int kk = 0; kk < 512; kk += 32) {
          bf16x8 bfrag = *(const bf16x8*)(wrow + 512 + kk);
#pragma unroll
          for (int r = 0; r < 4; ++r) {
            bf16x8 afrag = *(const bf16x8*)(abase + (r * 16 + nl) * H_ + kk);
            acc[r] = __builtin_amdgcn_mfma_f32_16x16x32_bf16(afrag, bfrag, acc[r], 0, 0, 0);
          }
        }
      }
      // ---- h0_t half ----
      wait_ge(spin0, (u32)(t + 1));
      __syncthreads();
      {
        const u16* abase = h0s + (size_t)(t & 3) * BH + quad * 8;
#pragma unroll 4
        for (int kk = 0; kk < 512; kk += 32) {
          bf16x8 bfrag = *(const bf16x8*)(wrow + kk);
#pragma unroll
          for (int r = 0; r < 4; ++r) {
            bf16x8 afrag = *(const bf16x8*)(abase + (r * 16 + nl) * H_ + kk);
            acc[r] = __builtin_amdgcn_mfma_f32_16x16x32_bf16(afrag, bfrag, acc[r], 0, 0, 0);
          }
        }
      }
    }

    // ---- gate combine via LDS (C/D layout: col=lane&15, row16=quad*4+i) ----
#pragma unroll
    for (int r = 0; r < 4; ++r)
#pragma unroll
      for (int i = 0; i < 4; ++i)
        lds[wave][r * 16 + quad * 4 + i][nl] = acc[r][i] + bias;
    __syncthreads();

    u16* hout = (unit == 0 ? h0s : h1s) + (size_t)(t & 3) * BH;
#pragma unroll
    for (int rr = 0; rr < 4; ++rr) {
      int row = rr * 16 + (tid >> 4);
      int col = tid & 15;
      float pi = lds[0][row][col];
      float pf = lds[1][row][col];
      float pg = lds[2][row][col];
      float po = lds[3][row][col];
      size_t sidx = (size_t)row * H_ + blk * 16 + col;
      float ig = sigm(pi);
      float fg = sigm(pf);
      float gg = tanh_(pg);
      float og = sigm(po);
      float cn = fg * creg[rr] + ig * gg;
      float hn = og * tanh_(cn);
      creg[rr] = cn;
      hout[sidx] = f2bf(hn);
      if (unit == 1) out[(size_t)t * BH + sidx] = hn;
      if (t == T_ - 1) {
        out[out_h_base + (size_t)unit * BH + sidx] = hn;
        out[out_c_base + (size_t)unit * BH + sidx] = cn;
      }
    }

    // ---- publish ----
    __threadfence();
    __syncthreads();
    if (tid == 0)
      __hip_atomic_store(myflag, (u32)(t + 1), __ATOMIC_RELEASE, __HIP_MEMORY_SCOPE_AGENT);
  }
}

extern "C" void kernel_launch(void* const* d_in, const int* in_sizes, int n_in,
                              void* d_out, int out_size, void* d_ws, size_t ws_size,
                              hipStream_t stream) {
  const float* x = (const float*)d_in[0];
  const float* Wx = (const float*)d_in[1];
  const float* Wh = (const float*)d_in[2];
  const float* bh = (const float*)d_in[3];
  float* out = (float*)d_out;
  char* ws = (char*)d_ws;

  // ws layout (bytes):
  u16* Wcat = (u16*)ws;                             // 8,388,608
  u16* xb = (u16*)(ws + 8388608);                   // 33,554,432
  u16* h0s = (u16*)(ws + 8388608 + 33554432);       // 4 slots * 65,536 = 262,144
  u16* h1s = (u16*)(ws + 8388608 + 33554432 + 262144);  // 262,144
  u32* flags = (u32*)(ws + 8388608 + 33554432 + 2 * 262144);  // 256
  // total ~42.5 MB

  conv_w_kernel<<<4096, 256, 0, stream>>>(Wx, Wh, Wcat);
  conv_x_kernel<<<16384, 256, 0, stream>>>((const float4*)x, xb);
  init_flags<<<1, 64, 0, stream>>>(flags);
  lstm_persist<<<64, 256, 0, stream>>>(Wcat, bh, xb, h0s, h1s, flags, out);
}

// Round 3
// 13590.602 us; speedup vs baseline: 1.0956x; 1.0956x over previous
//
#include <hip/hip_runtime.h>

// LSTM T=512 B=64 IN=512 H=512 L=2, fp32 in/out.
// Round 3: persistent kernel (64 blocks co-resident), cross-block sync via
// RELAXED agent-scope atomics only (cache-bypassing to Infinity Cache) — no
// acquire/release fences, so weights stay L2-hot (round 2's buffer_inv storm
// evicted them every step -> 29 us/step). h exchanged via packed b64 atomic
// stores/loads; h tile staged once per block into LDS; ordering via
// s_waitcnt vmcnt(0) + barrier before relaxed flag store.

typedef unsigned short u16;
typedef unsigned int u32;
typedef unsigned long long u64;
typedef __attribute__((ext_vector_type(8))) short bf16x8;
typedef __attribute__((ext_vector_type(4))) float floatx4;

#define T_ 512
#define B_ 64
#define H_ 512
#define BH (B_ * H_)
#define LDSP 520  // LDS row pitch in elements (+8 pad: rows offset 4 banks)

__device__ __forceinline__ u16 f2bf(float f) {
  u32 u = __float_as_uint(f);
  u32 r = (u + 0x7fffu + ((u >> 16) & 1u)) >> 16;  // RNE
  return (u16)r;
}

__device__ __forceinline__ float sigm(float x) { return 1.f / (1.f + __expf(-x)); }

__device__ __forceinline__ float tanh_(float x) {
  float ax = fabsf(x);
  float e = __expf(-2.f * ax);
  float t = (1.f - e) / (1.f + e);
  return copysignf(t, x);
}

// Wcat[l][row 0..2047][k 0..1023] bf16: k<512 from Wx, k>=512 from Wh.
__global__ void conv_w_kernel(const float* __restrict__ Wx, const float* __restrict__ Wh,
                              u16* __restrict__ Wcat) {
  int i = blockIdx.x * 256 + threadIdx.x;
  int base = i * 4;
  int k = base & 1023;
  int row = base >> 10;
  const float* src = (k < 512) ? (Wx + row * 512 + k) : (Wh + row * 512 + (k - 512));
  float4 v = *(const float4*)src;
  uint2 p;
  p.x = (u32)f2bf(v.x) | ((u32)f2bf(v.y) << 16);
  p.y = (u32)f2bf(v.z) | ((u32)f2bf(v.w) << 16);
  *(uint2*)(Wcat + base) = p;
}

__global__ void conv_x_kernel(const float4* __restrict__ x, u16* __restrict__ xb) {
  int i = blockIdx.x * 256 + threadIdx.x;
  float4 v = x[i];
  uint2 p;
  p.x = (u32)f2bf(v.x) | ((u32)f2bf(v.y) << 16);
  p.y = (u32)f2bf(v.z) | ((u32)f2bf(v.w) << 16);
  *(uint2*)(xb + i * 4) = p;
}

__global__ void init_flags(u32* flags) {
  if (threadIdx.x < 64) flags[threadIdx.x] = 0;
}

__device__ __forceinline__ u32 aload32(const u32* p) {
  return __hip_atomic_load(p, __ATOMIC_RELAXED, __HIP_MEMORY_SCOPE_AGENT);
}
__device__ __forceinline__ u64 aload64(const u64* p) {
  return __hip_atomic_load(p, __ATOMIC_RELAXED, __HIP_MEMORY_SCOPE_AGENT);
}
__device__ __forceinline__ void astore64(u64* p, u64 v) {
  __hip_atomic_store(p, v, __ATOMIC_RELAXED, __HIP_MEMORY_SCOPE_AGENT);
}

__device__ __forceinline__ void wait_ge(const u32* f, u32 target) {
  while (aload32(f) < target) __builtin_amdgcn_s_sleep(1);
}

// Stage a [64][512] bf16 h tile from global (coherent b64 loads, wave-contiguous
// 512B per instruction) into LDS with padded pitch.
__device__ __forceinline__ void stage_h(const u16* __restrict__ src, u16* lds, int tid) {
#pragma unroll 16
  for (int k = 0; k < 64; ++k) {
    int e = k * 1024 + tid * 4;  // element index; wave covers contiguous 512B
    u64 v = aload64((const u64*)(src + e));
    int row = e >> 9;
    int col = e & 511;
    *(u64*)(lds + row * LDSP + col) = v;
  }
}

// 64 blocks x 256 threads, persistent over all timesteps.
// unit = blockIdx>>5 (layer), blk = 16-col slice. Wave w = gate w.
// h0s/h1s: depth-4 slot buffers [4][64][512] bf16 (atomic-only access).
// flags[2][32] = per-slice completed-step counts.
__global__ __launch_bounds__(256) void lstm_persist(
    const u16* __restrict__ Wcat, const float* __restrict__ bh,
    const u16* __restrict__ xb, u16* __restrict__ h0s, u16* __restrict__ h1s,
    u32* flags, float* __restrict__ out) {
  const int unit = blockIdx.x >> 5;
  const int blk = blockIdx.x & 31;
  const int tid = threadIdx.x;
  const int wave = tid >> 6;
  const int lane = tid & 63;
  const int nl = lane & 15;
  const int quad = lane >> 4;

  const u16* wrow = Wcat + ((size_t)unit * 2048 + wave * 512 + blk * 16 + nl) * 1024 + quad * 8;
  const float bias = bh[unit * 2048 + wave * 512 + blk * 16 + nl];

  __shared__ u16 hstage[64 * LDSP];   // 66,560 B
  __shared__ float ldsg[4][64][17];   // 17,408 B

  // epilogue mapping: thread -> (row = tid>>2, 4 cols at (tid&3)*4)
  const int erow = tid >> 2;
  const int ec = (tid & 3) * 4;
  float creg[4] = {0.f, 0.f, 0.f, 0.f};

  u32* myflag = flags + unit * 32 + blk;
  const u32* f0 = flags;        // unit0 slice flags [32]
  const u32* f1 = flags + 32;   // unit1 slice flags [32]

  const size_t out_h_base = (size_t)T_ * BH;
  const size_t out_c_base = out_h_base + 2 * (size_t)BH;

  for (int t = 0; t < T_; ++t) {
    floatx4 acc[4] = {floatx4{0.f, 0.f, 0.f, 0.f}, floatx4{0.f, 0.f, 0.f, 0.f},
                      floatx4{0.f, 0.f, 0.f, 0.f}, floatx4{0.f, 0.f, 0.f, 0.f}};

    if (unit == 0) {
      // ---- x-half: dependency-free, overlaps peers' publish ----
      {
        const u16* abase = xb + (size_t)t * BH + quad * 8;
#pragma unroll 4
        for (int kk = 0; kk < 512; kk += 32) {
          bf16x8 bfrag = *(const bf16x8*)(wrow + kk);
#pragma unroll
          for (int r = 0; r < 4; ++r) {
            bf16x8 afrag = *(const bf16x8*)(abase + (r * 16 + nl) * H_ + kk);
            acc[r] = __builtin_amdgcn_mfma_f32_16x16x32_bf16(afrag, bfrag, acc[r], 0, 0, 0);
          }
        }
      }
      if (tid < 32) {
        if (t > 0) wait_ge(f0 + tid, (u32)t);        // h0_{t-1} complete
        if (t >= 4) wait_ge(f1 + tid, (u32)(t - 3)); // slot t&3 free of readers
      }
      __syncthreads();
      if (t > 0) {
        stage_h(h0s + (size_t)((t - 1) & 3) * BH, hstage, tid);
        __syncthreads();
#pragma unroll 4
        for (int kk = 0; kk < 512; kk += 32) {
          bf16x8 bfrag = *(const bf16x8*)(wrow + 512 + kk);
#pragma unroll
          for (int r = 0; r < 4; ++r) {
            bf16x8 afrag = *(const bf16x8*)(hstage + (r * 16 + nl) * LDSP + kk + quad * 8);
            acc[r] = __builtin_amdgcn_mfma_f32_16x16x32_bf16(afrag, bfrag, acc[r], 0, 0, 0);
          }
        }
      }
    } else {
      // ---- h1_{t-1} half first (available earliest) ----
      if (t > 0) {
        if (tid < 32) wait_ge(f1 + tid, (u32)t);
        __syncthreads();
        stage_h(h1s + (size_t)((t - 1) & 3) * BH, hstage, tid);
        __syncthreads();
#pragma unroll 4
        for (int kk = 0; kk < 512; kk += 32) {
          bf16x8 bfrag = *(const bf16x8*)(wrow + 512 + kk);
#pragma unroll
          for (int r = 0; r < 4; ++r) {
            bf16x8 afrag = *(const bf16x8*)(hstage + (r * 16 + nl) * LDSP + kk + quad * 8);
            acc[r] = __builtin_amdgcn_mfma_f32_16x16x32_bf16(afrag, bfrag, acc[r], 0, 0, 0);
          }
        }
      }
      // ---- h0_t half ----
      if (tid < 32) wait_ge(f0 + tid, (u32)(t + 1));
      __syncthreads();
      stage_h(h0s + (size_t)(t & 3) * BH, hstage, tid);
      __syncthreads();
#pragma unroll 4
      for (int kk = 0; kk < 512; kk += 32) {
        bf16x8 bfrag = *(const bf16x8*)(wrow + kk);
#pragma unroll
        for (int r = 0; r < 4; ++r) {
          bf16x8 afrag = *(const bf16x8*)(hstage + (r * 16 + nl) * LDSP + kk + quad * 8);
          acc[r] = __builtin_amdgcn_mfma_f32_16x16x32_bf16(afrag, bfrag, acc[r], 0, 0, 0);
        }
      }
    }

    // ---- gate combine (C/D layout: col=lane&15, row16=quad*4+i) ----
#pragma unroll
    for (int r = 0; r < 4; ++r)
#pragma unroll
      for (int i = 0; i < 4; ++i)
        ldsg[wave][r * 16 + quad * 4 + i][nl] = acc[r][i] + bias;
    __syncthreads();

    u16* hout = (unit == 0 ? h0s : h1s) + (size_t)(t & 3) * BH;
    float hn[4], cn[4];
#pragma unroll
    for (int j = 0; j < 4; ++j) {
      float pi = ldsg[0][erow][ec + j];
      float pf = ldsg[1][erow][ec + j];
      float pg = ldsg[2][erow][ec + j];
      float po = ldsg[3][erow][ec + j];
      float ig = sigm(pi);
      float fg = sigm(pf);
      float gg = tanh_(pg);
      float og = sigm(po);
      cn[j] = fg * creg[j] + ig * gg;
      hn[j] = og * tanh_(cn[j]);
      creg[j] = cn[j];
    }
    // packed b64 coherent publish of 4 bf16
    u64 pk = (u64)f2bf(hn[0]) | ((u64)f2bf(hn[1]) << 16) |
             ((u64)f2bf(hn[2]) << 32) | ((u64)f2bf(hn[3]) << 48);
    size_t sidx = (size_t)erow * H_ + blk * 16 + ec;
    astore64((u64*)(hout + sidx), pk);
    if (unit == 1)
      *(float4*)(out + (size_t)t * BH + sidx) = make_float4(hn[0], hn[1], hn[2], hn[3]);
    if (t == T_ - 1) {
      *(float4*)(out + out_h_base + (size_t)unit * BH + sidx) =
          make_float4(hn[0], hn[1], hn[2], hn[3]);
      *(float4*)(out + out_c_base + (size_t)unit * BH + sidx) =
          make_float4(cn[0], cn[1], cn[2], cn[3]);
    }

    // ---- publish: drain payload stores, then relaxed flag store ----
    asm volatile("s_waitcnt vmcnt(0)" ::: "memory");
    __syncthreads();
    if (tid == 0)
      __hip_atomic_store(myflag, (u32)(t + 1), __ATOMIC_RELAXED, __HIP_MEMORY_SCOPE_AGENT);
  }
}

extern "C" void kernel_launch(void* const* d_in, const int* in_sizes, int n_in,
                              void* d_out, int out_size, void* d_ws, size_t ws_size,
                              hipStream_t stream) {
  const float* x = (const float*)d_in[0];
  const float* Wx = (const float*)d_in[1];
  const float* Wh = (const float*)d_in[2];
  const float* bh = (const float*)d_in[3];
  float* out = (float*)d_out;
  char* ws = (char*)d_ws;

  u16* Wcat = (u16*)ws;                                  // 8,388,608 B
  u16* xb = (u16*)(ws + 8388608);                        // 33,554,432 B
  u16* h0s = (u16*)(ws + 8388608 + 33554432);            // 262,144 B (4 slots)
  u16* h1s = (u16*)(ws + 8388608 + 33554432 + 262144);   // 262,144 B
  u32* flags = (u32*)(ws + 8388608 + 33554432 + 2 * 262144);  // 256 B

  conv_w_kernel<<<4096, 256, 0, stream>>>(Wx, Wh, Wcat);
  conv_x_kernel<<<16384, 256, 0, stream>>>((const float4*)x, xb);
  init_flags<<<1, 64, 0, stream>>>(flags);
  lstm_persist<<<64, 256, 0, stream>>>(Wcat, bh, xb, h0s, h1s, flags, out);
}

// Round 4
// 4344.223 us; speedup vs baseline: 3.4275x; 3.1284x over previous
//
#include <hip/hip_runtime.h>

// LSTM T=512 B=64 IN=512 H=512 L=2, fp32 in/out.
// Round 4: persistent kernel, 128 blocks (64 per layer-unit, 8 h-cols each).
// Per-block W slice (32 rows x 1024 K, bf16 = 64 KB) lives in LDS for the whole
// kernel; per step the only serial-chain global traffic is the h exchange
// (relaxed agent-scope atomics via MALL) + flag handshake. unit1's two halves
// (h1_{t-1}, then h0_t) each: wait -> stage 64KB with full MLP -> LDS GEMM.
// d_out stores issued after the flag publish (off the critical chain).

typedef unsigned short u16;
typedef unsigned int u32;
typedef unsigned long long u64;
typedef __attribute__((ext_vector_type(8))) short bf16x8;
typedef __attribute__((ext_vector_type(4))) float floatx4;

#define T_ 512
#define B_ 64
#define H_ 512
#define BH (B_ * H_)
#define WP 1032  // W LDS pitch (elems): 1024 + 8 pad -> row stride 4 banks
#define HP 520   // hstage pitch (elems): 512 + 8 pad

__device__ __forceinline__ u16 f2bf(float f) {
  u32 u = __float_as_uint(f);
  u32 r = (u + 0x7fffu + ((u >> 16) & 1u)) >> 16;  // RNE
  return (u16)r;
}

__device__ __forceinline__ float sigm(float x) { return 1.f / (1.f + __expf(-x)); }

__device__ __forceinline__ float tanh_(float x) {
  float ax = fabsf(x);
  float e = __expf(-2.f * ax);
  float t = (1.f - e) / (1.f + e);
  return copysignf(t, x);
}

// Wcat[l][row 0..2047][k 0..1023] bf16: k<512 from Wx, k>=512 from Wh.
__global__ void conv_w_kernel(const float* __restrict__ Wx, const float* __restrict__ Wh,
                              u16* __restrict__ Wcat) {
  int i = blockIdx.x * 256 + threadIdx.x;
  int base = i * 4;
  int k = base & 1023;
  int row = base >> 10;
  const float* src = (k < 512) ? (Wx + row * 512 + k) : (Wh + row * 512 + (k - 512));
  float4 v = *(const float4*)src;
  uint2 p;
  p.x = (u32)f2bf(v.x) | ((u32)f2bf(v.y) << 16);
  p.y = (u32)f2bf(v.z) | ((u32)f2bf(v.w) << 16);
  *(uint2*)(Wcat + base) = p;
}

__global__ void conv_x_kernel(const float4* __restrict__ x, u16* __restrict__ xb) {
  int i = blockIdx.x * 256 + threadIdx.x;
  float4 v = x[i];
  uint2 p;
  p.x = (u32)f2bf(v.x) | ((u32)f2bf(v.y) << 16);
  p.y = (u32)f2bf(v.z) | ((u32)f2bf(v.w) << 16);
  *(uint2*)(xb + i * 4) = p;
}

__global__ void init_flags(u32* flags) {
  if (threadIdx.x < 128) flags[threadIdx.x] = 0;
}

__device__ __forceinline__ u32 aload32(const u32* p) {
  return __hip_atomic_load(p, __ATOMIC_RELAXED, __HIP_MEMORY_SCOPE_AGENT);
}
__device__ __forceinline__ u64 aload64(const u64* p) {
  return __hip_atomic_load(p, __ATOMIC_RELAXED, __HIP_MEMORY_SCOPE_AGENT);
}
__device__ __forceinline__ void astore32(u32* p, u32 v) {
  __hip_atomic_store(p, v, __ATOMIC_RELAXED, __HIP_MEMORY_SCOPE_AGENT);
}

__device__ __forceinline__ void wait_ge(const u32* f, u32 target) {
  while (aload32(f) < target) {
  }
}

// Stage the [64][512] bf16 h tile (64 KB) from MALL into LDS, full MLP:
// all 32 b64 loads issued before any use. Exactly covers 32768 elements.
__device__ __forceinline__ void stage_h(const u16* __restrict__ src, u16* dst, int tid) {
  u64 tmp[32];
#pragma unroll
  for (int i = 0; i < 32; ++i)
    tmp[i] = aload64((const u64*)(src + i * 1024 + tid * 4));
#pragma unroll
  for (int i = 0; i < 32; ++i) {
    int row = i * 2 + (tid >> 7);
    int col = (tid & 127) * 4;
    *(u64*)(dst + row * HP + col) = tmp[i];
  }
}

// 128 blocks x 256 threads. unit = blockIdx&1 (layer), cg = blockIdx>>1 (8-col
// group). Wave (bt = wave>>1: batch half, nt = wave&1: 16-row W tile).
// Logical W row r' = gate*8 + col (0..31). flags[2][64] = step counters.
__global__ __launch_bounds__(256) void lstm_persist(
    const u16* __restrict__ Wcat, const float* __restrict__ bh,
    const u16* __restrict__ xb, u16* __restrict__ h0s, u16* __restrict__ h1s,
    u32* flags, float* __restrict__ out) {
  const int unit = blockIdx.x & 1;
  const int cg = blockIdx.x >> 1;
  const int colbase = cg * 8;
  const int tid = threadIdx.x;
  const int wave = tid >> 6;
  const int lane = tid & 63;
  const int nl = lane & 15;
  const int quad = lane >> 4;
  const int bt = wave >> 1;
  const int nt = wave & 1;

  __shared__ u16 Wlds[32 * WP];     // 66,048 B
  __shared__ u16 hstage[64 * HP];   // 66,560 B
  __shared__ float ldsg[32][66];    //  8,448 B

  // ---- stage W slice once: r' = g*8+c -> Wcat row unit*2048 + g*512 + colbase + c
  for (int it = 0; it < 16; ++it) {
    int gid = it * 256 + tid;  // 4096 granules of 8 elems
    int r = gid >> 7;
    int col = (gid & 127) * 8;
    const u16* src = Wcat + ((size_t)unit * 2048 + (r >> 3) * 512 + colbase + (r & 7)) * 1024 + col;
    *(bf16x8*)(Wlds + r * WP + col) = *(const bf16x8*)src;
  }
  // bias for this lane's W row r' = nt*16+nl
  const int rp = nt * 16 + nl;
  const float bias = bh[unit * 2048 + (rp >> 3) * 512 + colbase + (rp & 7)];
  __syncthreads();

  float creg[2] = {0.f, 0.f};  // c for (batch = tid>>2, cols colbase + (tid&3)*2 + {0,1})
  const int eb = tid >> 2;
  const int ec = (tid & 3) * 2;

  const u32* f0 = flags;
  const u32* f1 = flags + 64;
  u32* myflag = flags + unit * 64 + cg;

  const size_t out_h_base = (size_t)T_ * BH;
  const size_t out_c_base = out_h_base + 2 * (size_t)BH;

  for (int t = 0; t < T_; ++t) {
    floatx4 acc[2] = {floatx4{0.f, 0.f, 0.f, 0.f}, floatx4{0.f, 0.f, 0.f, 0.f}};

    if (unit == 0) {
      // ---- x-half: A from global xb (L2), B cols 0..511 from LDS ----
      {
        const u16* xt = xb + (size_t)t * BH;
#pragma unroll 4
        for (int kk = 0; kk < 512; kk += 32) {
          bf16x8 bfrag = *(const bf16x8*)(Wlds + rp * WP + kk + quad * 8);
#pragma unroll
          for (int j = 0; j < 2; ++j) {
            const u16* ap = xt + (bt * 32 + j * 16 + nl) * 512 + kk + quad * 8;
            acc[j] = __builtin_amdgcn_mfma_f32_16x16x32_bf16(*(const bf16x8*)ap, bfrag, acc[j], 0, 0, 0);
          }
        }
      }
      if (tid < 64) {
        if (t > 0) wait_ge(f0 + tid, (u32)t);          // peers' h0_{t-1}
        if (t >= 4) wait_ge(f1 + tid, (u32)(t - 3));   // slot t&3 consumed
      }
      __syncthreads();
      if (t > 0) {
        stage_h(h0s + (size_t)((t - 1) & 3) * BH, hstage, tid);
        __syncthreads();
#pragma unroll 4
        for (int kk = 0; kk < 512; kk += 32) {
          bf16x8 bfrag = *(const bf16x8*)(Wlds + rp * WP + 512 + kk + quad * 8);
#pragma unroll
          for (int j = 0; j < 2; ++j) {
            const u16* ap = hstage + (bt * 32 + j * 16 + nl) * HP + kk + quad * 8;
            acc[j] = __builtin_amdgcn_mfma_f32_16x16x32_bf16(*(const bf16x8*)ap, bfrag, acc[j], 0, 0, 0);
          }
        }
      }
    } else {
      // ---- h1_{t-1} half (own-unit peers; flag usually already set) ----
      if (t > 0) {
        if (tid < 64) wait_ge(f1 + tid, (u32)t);
        __syncthreads();
        stage_h(h1s + (size_t)((t - 1) & 3) * BH, hstage, tid);
        __syncthreads();
#pragma unroll 4
        for (int kk = 0; kk < 512; kk += 32) {
          bf16x8 bfrag = *(const bf16x8*)(Wlds + rp * WP + 512 + kk + quad * 8);
#pragma unroll
          for (int j = 0; j < 2; ++j) {
            const u16* ap = hstage + (bt * 32 + j * 16 + nl) * HP + kk + quad * 8;
            acc[j] = __builtin_amdgcn_mfma_f32_16x16x32_bf16(*(const bf16x8*)ap, bfrag, acc[j], 0, 0, 0);
          }
        }
      }
      // ---- h0_t half (cross-unit; the critical hop) ----
      if (tid < 64) wait_ge(f0 + tid, (u32)(t + 1));
      __syncthreads();
      stage_h(h0s + (size_t)(t & 3) * BH, hstage, tid);
      __syncthreads();
#pragma unroll 4
      for (int kk = 0; kk < 512; kk += 32) {
        bf16x8 bfrag = *(const bf16x8*)(Wlds + rp * WP + kk + quad * 8);
#pragma unroll
        for (int j = 0; j < 2; ++j) {
          const u16* ap = hstage + (bt * 32 + j * 16 + nl) * HP + kk + quad * 8;
          acc[j] = __builtin_amdgcn_mfma_f32_16x16x32_bf16(*(const bf16x8*)ap, bfrag, acc[j], 0, 0, 0);
        }
      }
    }

    // ---- gate combine (C/D: col=lane&15 -> W row, row16=quad*4+i -> batch) ----
#pragma unroll
    for (int j = 0; j < 2; ++j)
#pragma unroll
      for (int i = 0; i < 4; ++i)
        ldsg[rp][bt * 32 + j * 16 + quad * 4 + i] = acc[j][i] + bias;
    __syncthreads();

    float hn[2], cn[2];
#pragma unroll
    for (int k = 0; k < 2; ++k) {
      int cc = ec + k;
      float pi = ldsg[cc][eb];
      float pf = ldsg[8 + cc][eb];
      float pg = ldsg[16 + cc][eb];
      float po = ldsg[24 + cc][eb];
      float ig = sigm(pi);
      float fg = sigm(pf);
      float gg = tanh_(pg);
      float og = sigm(po);
      cn[k] = fg * creg[k] + ig * gg;
      hn[k] = og * tanh_(cn[k]);
      creg[k] = cn[k];
    }
    // ---- publish h (critical), then flag, then off-chain d_out stores ----
    u16* hout = (unit == 0 ? h0s : h1s) + (size_t)(t & 3) * BH;
    u32 pk = (u32)f2bf(hn[0]) | ((u32)f2bf(hn[1]) << 16);
    astore32((u32*)(hout + eb * 512 + colbase + ec), pk);
    asm volatile("s_waitcnt vmcnt(0)" ::: "memory");
    __syncthreads();
    if (tid == 0) astore32(myflag, (u32)(t + 1));

    size_t sidx = (size_t)eb * H_ + colbase + ec;
    if (unit == 1)
      *(float2*)(out + (size_t)t * BH + sidx) = make_float2(hn[0], hn[1]);
    if (t == T_ - 1) {
      *(float2*)(out + out_h_base + (size_t)unit * BH + sidx) = make_float2(hn[0], hn[1]);
      *(float2*)(out + out_c_base + (size_t)unit * BH + sidx) = make_float2(cn[0], cn[1]);
    }
  }
}

extern "C" void kernel_launch(void* const* d_in, const int* in_sizes, int n_in,
                              void* d_out, int out_size, void* d_ws, size_t ws_size,
                              hipStream_t stream) {
  const float* x = (const float*)d_in[0];
  const float* Wx = (const float*)d_in[1];
  const float* Wh = (const float*)d_in[2];
  const float* bh = (const float*)d_in[3];
  float* out = (float*)d_out;
  char* ws = (char*)d_ws;

  u16* Wcat = (u16*)ws;                                  // 8,388,608 B
  u16* xb = (u16*)(ws + 8388608);                        // 33,554,432 B
  u16* h0s = (u16*)(ws + 8388608 + 33554432);            // 262,144 B (4 slots)
  u16* h1s = (u16*)(ws + 8388608 + 33554432 + 262144);   // 262,144 B
  u32* flags = (u32*)(ws + 8388608 + 33554432 + 2 * 262144);  // 512 B

  conv_w_kernel<<<4096, 256, 0, stream>>>(Wx, Wh, Wcat);
  conv_x_kernel<<<16384, 256, 0, stream>>>((const float4*)x, xb);
  init_flags<<<1, 128, 0, stream>>>(flags);
  lstm_persist<<<128, 256, 0, stream>>>(Wcat, bh, xb, h0s, h1s, flags, out);
}

// Round 5
// 4220.435 us; speedup vs baseline: 3.5280x; 1.0293x over previous
//
#include <hip/hip_runtime.h>

// LSTM T=512 B=64 IN=512 H=512 L=2, fp32 in/out.
// Round 5: persistent kernel, 128 blocks (1/CU). 32x32x16 MFMA; W fragments
// live in VGPRs (128/wave, loop-invariant). Waves = (batch-tile bt, K-half kh);
// kh partials summed in the LDS gate-combine. unit0 kh0 = x-half from global
// (issued before waits); h halves staged to LDS via relaxed agent atomics.
// Publish: rows packed in LDS, wave0 does 2xb64 coherent stores/row, vmcnt(0),
// lane0 flag. Spin loops back off with s_sleep(1).

typedef unsigned short u16;
typedef unsigned int u32;
typedef unsigned long long u64;
typedef __attribute__((ext_vector_type(8))) short bf16x8;
typedef __attribute__((ext_vector_type(4))) float floatx4;
typedef __attribute__((ext_vector_type(16))) float floatx16;

#define T_ 512
#define B_ 64
#define H_ 512
#define BH (B_ * H_)
#define HP 528  // hstage pitch (elems): 512+16 -> row stride 1056 B (16B-mult)

__device__ __forceinline__ u16 f2bf(float f) {
  u32 u = __float_as_uint(f);
  u32 r = (u + 0x7fffu + ((u >> 16) & 1u)) >> 16;  // RNE
  return (u16)r;
}

__device__ __forceinline__ float sigm(float x) { return 1.f / (1.f + __expf(-x)); }

__device__ __forceinline__ float tanh_(float x) {
  float ax = fabsf(x);
  float e = __expf(-2.f * ax);
  float t = (1.f - e) / (1.f + e);
  return copysignf(t, x);
}

// Wcat[l][row 0..2047][k 0..1023] bf16: k<512 from Wx, k>=512 from Wh.
__global__ void conv_w_kernel(const float* __restrict__ Wx, const float* __restrict__ Wh,
                              u16* __restrict__ Wcat) {
  int i = blockIdx.x * 256 + threadIdx.x;
  int base = i * 4;
  int k = base & 1023;
  int row = base >> 10;
  const float* src = (k < 512) ? (Wx + row * 512 + k) : (Wh + row * 512 + (k - 512));
  float4 v = *(const float4*)src;
  uint2 p;
  p.x = (u32)f2bf(v.x) | ((u32)f2bf(v.y) << 16);
  p.y = (u32)f2bf(v.z) | ((u32)f2bf(v.w) << 16);
  *(uint2*)(Wcat + base) = p;
}

__global__ void conv_x_kernel(const float4* __restrict__ x, u16* __restrict__ xb) {
  int i = blockIdx.x * 256 + threadIdx.x;
  float4 v = x[i];
  uint2 p;
  p.x = (u32)f2bf(v.x) | ((u32)f2bf(v.y) << 16);
  p.y = (u32)f2bf(v.z) | ((u32)f2bf(v.w) << 16);
  *(uint2*)(xb + i * 4) = p;
}

__global__ void init_flags(u32* flags) {
  if (threadIdx.x < 128) flags[threadIdx.x] = 0;
}

__device__ __forceinline__ u32 aload32(const u32* p) {
  return __hip_atomic_load(p, __ATOMIC_RELAXED, __HIP_MEMORY_SCOPE_AGENT);
}
__device__ __forceinline__ u64 aload64(const u64* p) {
  return __hip_atomic_load(p, __ATOMIC_RELAXED, __HIP_MEMORY_SCOPE_AGENT);
}
__device__ __forceinline__ void astore32(u32* p, u32 v) {
  __hip_atomic_store(p, v, __ATOMIC_RELAXED, __HIP_MEMORY_SCOPE_AGENT);
}
__device__ __forceinline__ void astore64(u64* p, u64 v) {
  __hip_atomic_store(p, v, __ATOMIC_RELAXED, __HIP_MEMORY_SCOPE_AGENT);
}

__device__ __forceinline__ void wait_ge(const u32* f, u32 target) {
  while (aload32(f) < target) __builtin_amdgcn_s_sleep(1);
}

// Stage [64][512] bf16 (64 KB) from MALL into LDS (pitch HP). 32 b64/thread.
__device__ __forceinline__ void stage_h(const u16* __restrict__ src, u16* dst, int tid) {
  u64 tmp[32];
#pragma unroll
  for (int i = 0; i < 32; ++i)
    tmp[i] = aload64((const u64*)(src + i * 1024 + tid * 4));
#pragma unroll
  for (int i = 0; i < 32; ++i) {
    int row = i * 2 + (tid >> 7);
    int col = (tid & 127) * 4;
    *(u64*)(dst + row * HP + col) = tmp[i];
  }
}

// 128 blocks x 256 threads (1 block/CU). unit=blockIdx&1, cg=blockIdx>>1.
// Wave: bt=wave&1 (batch 32-tile), kh=wave>>1 (K-half). Logical W row
// rp = gate*8 + localcol (0..31). flags[2][64] = per-block step counters.
__global__ __launch_bounds__(256, 1) void lstm_persist(
    const u16* __restrict__ Wcat, const float* __restrict__ bh,
    const u16* __restrict__ xb, u16* __restrict__ h0s, u16* __restrict__ h1s,
    u32* flags, float* __restrict__ out) {
  const int unit = blockIdx.x & 1;
  const int cg = blockIdx.x >> 1;
  const int colbase = cg * 8;
  const int tid = threadIdx.x;
  const int wave = tid >> 6;
  const int bt = wave & 1;
  const int kh = wave >> 1;
  const int lane = tid & 63;
  const int l31 = lane & 31;
  const int lh = lane >> 5;

  __shared__ u16 hstage[64 * HP];      // 67,584 B
  __shared__ float ldsg[4 * 32 * 36];  // 18,432 B [bt*2+kh][Wrow 32][batch 36p]
  __shared__ u32 hpub[256];            //  1,024 B [row 64][4 packed pairs]

  // ---- W fragments into VGPRs (loop-invariant). B[k][col]: col=lane&31 -> W
  // row rp; k = kh*512 + i*16 + lh*8 + j (8 contiguous k -> one b128).
  bf16x8 w[32];
  {
    const int rp = l31;
    const u16* wbase = Wcat + ((size_t)unit * 2048 + (rp >> 3) * 512 + colbase + (rp & 7)) * 1024 +
                       kh * 512 + lh * 8;
#pragma unroll
    for (int i = 0; i < 32; ++i) w[i] = *(const bf16x8*)(wbase + i * 16);
  }

  // epilogue ownership: batch eb = tid>>2, 2 cols ec..ec+1 (ec=(tid&3)*2)
  const int eb = tid >> 2;
  const int ebt = eb >> 5;
  const int eb32 = eb & 31;
  const int ec = (tid & 3) * 2;
  float bias[4][2];
#pragma unroll
  for (int g = 0; g < 4; ++g)
#pragma unroll
    for (int cc = 0; cc < 2; ++cc)
      bias[g][cc] = bh[unit * 2048 + g * 512 + colbase + ec + cc];

  float creg[2] = {0.f, 0.f};

  const u32* f0 = flags;
  const u32* f1 = flags + 64;
  u32* myflag = flags + unit * 64 + cg;

  const size_t out_h_base = (size_t)T_ * BH;
  const size_t out_c_base = out_h_base + 2 * (size_t)BH;

  for (int t = 0; t < T_; ++t) {
    floatx16 acc = {0.f, 0.f, 0.f, 0.f, 0.f, 0.f, 0.f, 0.f,
                    0.f, 0.f, 0.f, 0.f, 0.f, 0.f, 0.f, 0.f};

    if (unit == 0) {
      // ---- kh0 waves: x-half from global (no dependency; before any wait) ----
      if (kh == 0) {
        const u16* abase = xb + (size_t)t * BH + (bt * 32 + l31) * 512 + lh * 8;
#pragma unroll
        for (int i = 0; i < 32; ++i) {
          bf16x8 a = *(const bf16x8*)(abase + i * 16);
          acc = __builtin_amdgcn_mfma_f32_32x32x16_bf16(a, w[i], acc, 0, 0, 0);
        }
      }
      if (tid < 64) {
        if (t > 0) wait_ge(f0 + tid, (u32)t);         // peers' h0_{t-1}
        if (t >= 4) wait_ge(f1 + tid, (u32)(t - 3));  // slot t&3 consumed
      }
      __syncthreads();
      if (t > 0) {
        stage_h(h0s + (size_t)((t - 1) & 3) * BH, hstage, tid);
        __syncthreads();
        if (kh == 1) {
          const u16* abase = hstage + (bt * 32 + l31) * HP + lh * 8;
#pragma unroll
          for (int i = 0; i < 32; ++i) {
            bf16x8 a = *(const bf16x8*)(abase + i * 16);
            acc = __builtin_amdgcn_mfma_f32_32x32x16_bf16(a, w[i], acc, 0, 0, 0);
          }
        }
      }
    } else {
      // ---- h1_{t-1} half (kh1 W covers K 512..1023 = Wh1) ----
      if (t > 0) {
        if (tid < 64) wait_ge(f1 + tid, (u32)t);
        __syncthreads();
        stage_h(h1s + (size_t)((t - 1) & 3) * BH, hstage, tid);
        __syncthreads();
        if (kh == 1) {
          const u16* abase = hstage + (bt * 32 + l31) * HP + lh * 8;
#pragma unroll
          for (int i = 0; i < 32; ++i) {
            bf16x8 a = *(const bf16x8*)(abase + i * 16);
            acc = __builtin_amdgcn_mfma_f32_32x32x16_bf16(a, w[i], acc, 0, 0, 0);
          }
        }
      }
      // ---- h0_t half (kh0 W covers K 0..511 = Wx1; the critical hop) ----
      if (tid < 64) wait_ge(f0 + tid, (u32)(t + 1));
      __syncthreads();
      stage_h(h0s + (size_t)(t & 3) * BH, hstage, tid);
      __syncthreads();
      if (kh == 0) {
        const u16* abase = hstage + (bt * 32 + l31) * HP + lh * 8;
#pragma unroll
        for (int i = 0; i < 32; ++i) {
          bf16x8 a = *(const bf16x8*)(abase + i * 16);
          acc = __builtin_amdgcn_mfma_f32_32x32x16_bf16(a, w[i], acc, 0, 0, 0);
        }
      }
    }

    // ---- write kh partials: C/D row=(reg&3)+8*(reg>>2)+4*lh, col=lane&31 ----
    {
      float* lg = ldsg + (bt * 2 + kh) * 1152 + l31 * 36 + 4 * lh;
#pragma unroll
      for (int rg = 0; rg < 4; ++rg)
        *(floatx4*)(lg + 8 * rg) =
            floatx4{acc[rg * 4 + 0], acc[rg * 4 + 1], acc[rg * 4 + 2], acc[rg * 4 + 3]};
    }
    __syncthreads();

    // ---- epilogue: sum kh partials + bias, gate math, c in regs ----
    float hn[2], cn[2];
#pragma unroll
    for (int cc = 0; cc < 2; ++cc) {
      int c = ec + cc;
      float pi = ldsg[(ebt * 2 + 0) * 1152 + (0 * 8 + c) * 36 + eb32] +
                 ldsg[(ebt * 2 + 1) * 1152 + (0 * 8 + c) * 36 + eb32] + bias[0][cc];
      float pf = ldsg[(ebt * 2 + 0) * 1152 + (1 * 8 + c) * 36 + eb32] +
                 ldsg[(ebt * 2 + 1) * 1152 + (1 * 8 + c) * 36 + eb32] + bias[1][cc];
      float pg = ldsg[(ebt * 2 + 0) * 1152 + (2 * 8 + c) * 36 + eb32] +
                 ldsg[(ebt * 2 + 1) * 1152 + (2 * 8 + c) * 36 + eb32] + bias[2][cc];
      float po = ldsg[(ebt * 2 + 0) * 1152 + (3 * 8 + c) * 36 + eb32] +
                 ldsg[(ebt * 2 + 1) * 1152 + (3 * 8 + c) * 36 + eb32] + bias[3][cc];
      float ig = sigm(pi);
      float fg = sigm(pf);
      float gg = tanh_(pg);
      float og = sigm(po);
      cn[cc] = fg * creg[cc] + ig * gg;
      hn[cc] = og * tanh_(cn[cc]);
      creg[cc] = cn[cc];
    }
    hpub[tid] = (u32)f2bf(hn[0]) | ((u32)f2bf(hn[1]) << 16);  // = hpub[eb][tid&3]
    __syncthreads();

    // ---- wave0 publishes h rows (2xb64/row), drains, releases flag ----
    u16* hout = (unit == 0 ? h0s : h1s) + (size_t)(t & 3) * BH;
    if (tid < 64) {
      const u32* hp = hpub + tid * 4;
      u64 a = *(const u64*)hp;
      u64 b = *(const u64*)(hp + 2);
      u16* dst = hout + tid * 512 + colbase;
      astore64((u64*)dst, a);
      astore64((u64*)(dst + 4), b);
      asm volatile("s_waitcnt vmcnt(0)" ::: "memory");
      if (tid == 0) astore32(myflag, (u32)(t + 1));
    }

    // ---- off-chain d_out stores ----
    size_t sidx = (size_t)eb * H_ + colbase + ec;
    if (unit == 1)
      *(float2*)(out + (size_t)t * BH + sidx) = make_float2(hn[0], hn[1]);
    if (t == T_ - 1) {
      *(float2*)(out + out_h_base + (size_t)unit * BH + sidx) = make_float2(hn[0], hn[1]);
      *(float2*)(out + out_c_base + (size_t)unit * BH + sidx) = make_float2(cn[0], cn[1]);
    }
  }
}

extern "C" void kernel_launch(void* const* d_in, const int* in_sizes, int n_in,
                              void* d_out, int out_size, void* d_ws, size_t ws_size,
                              hipStream_t stream) {
  const float* x = (const float*)d_in[0];
  const float* Wx = (const float*)d_in[1];
  const float* Wh = (const float*)d_in[2];
  const float* bh = (const float*)d_in[3];
  float* out = (float*)d_out;
  char* ws = (char*)d_ws;

  u16* Wcat = (u16*)ws;                                  // 8,388,608 B
  u16* xb = (u16*)(ws + 8388608);                        // 33,554,432 B
  u16* h0s = (u16*)(ws + 8388608 + 33554432);            // 262,144 B (4 slots)
  u16* h1s = (u16*)(ws + 8388608 + 33554432 + 262144);   // 262,144 B
  u32* flags = (u32*)(ws + 8388608 + 33554432 + 2 * 262144);  // 512 B

  conv_w_kernel<<<4096, 256, 0, stream>>>(Wx, Wh, Wcat);
  conv_x_kernel<<<16384, 256, 0, stream>>>((const float4*)x, xb);
  init_flags<<<1, 128, 0, stream>>>(flags);
  lstm_persist<<<128, 256, 0, stream>>>(Wcat, bh, xb, h0s, h1s, flags, out);
}